// Round 1
// baseline (613.103 us; speedup 1.0000x reference)
//
#include <hip/hip_runtime.h>
#include <stdint.h>

// SequentialMLP (grouped MoE LLaMA-MLP), MI355X gfx950.
// E=64 experts x C=512 tokens each (equal-count setup), H=F=1024, f32 in/out.
// Strategy: bf16 MFMA GEMMs. Kernel1 = fused gate+up GEMM + silu*up -> h (bf16, d_ws).
// Kernel2 = down GEMM -> out (f32). Reg-staged LDS with f32->bf16 convert and
// T2 XOR swizzle (16B granule) on LDS tiles; T14-lite load/compute overlap.

#define NUM_E 64
#define DIM_H 1024
#define DIM_F 1024
#define CAP   512
#define NTOK  32768

typedef short short8 __attribute__((ext_vector_type(8)));
typedef float f32x4 __attribute__((ext_vector_type(4)));

__device__ __forceinline__ uint32_t bfpair(float a, float b) {
  uint32_t ua = __builtin_bit_cast(uint32_t, a);
  uint32_t ub = __builtin_bit_cast(uint32_t, b);
  ua += 0x7FFFu + ((ua >> 16) & 1u);   // RNE
  ub += 0x7FFFu + ((ub >> 16) & 1u);
  return (ua >> 16) | (ub & 0xFFFF0000u);
}
__device__ __forceinline__ unsigned short f2bf(float a) {
  uint32_t ua = __builtin_bit_cast(uint32_t, a);
  ua += 0x7FFFu + ((ua >> 16) & 1u);
  return (unsigned short)(ua >> 16);
}

// ---------------- Kernel 1: h = silu(x Wg) * (x Wu), bf16 out ----------------
// Tile: BM=128 tokens x BN=64 (per matrix) x BK=64. 4 waves; wave tile 64x32 per matrix.
__global__ __launch_bounds__(256, 2) void gateup_kernel(
    const float* __restrict__ x, const float* __restrict__ wg,
    const float* __restrict__ wu, unsigned short* __restrict__ hout)
{
  __shared__ unsigned char smem[32768]; // As[128][64]bf16 16KB | Bg^T[64][64] 8KB | Bu^T 8KB
  const int t = threadIdx.x;
  const int bid = blockIdx.x;
  const int e = bid >> 6, rr = bid & 63, mb = rr >> 4, nb = rr & 15;
  const int row0 = e * CAP + mb * 128;
  const int col0 = nb * 64;
  const float* Ag  = x  + (size_t)row0 * DIM_H;
  const float* Bgg = wg + (size_t)e * DIM_H * DIM_F + col0;
  const float* Bug = wu + (size_t)e * DIM_H * DIM_F + col0;

  const int lane = t & 63, wid = t >> 6;
  const int wm = wid >> 1, wn = wid & 1;

  f32x4 accg[4][2], accu[4][2];
  #pragma unroll
  for (int i = 0; i < 4; i++)
    #pragma unroll
    for (int j = 0; j < 2; j++) {
      accg[i][j] = f32x4{0.f, 0.f, 0.f, 0.f};
      accu[i][j] = f32x4{0.f, 0.f, 0.f, 0.f};
    }

  f32x4 ast[8];
  float bgst[16], bust[16];
  const int bn = t & 63, bkb = (t >> 6) * 4;

  auto loadT = [&](int k0) {
    #pragma unroll
    for (int p = 0; p < 8; p++) {     // A tile: 128x64 f32, 16 threads/row
      int g = p * 256 + t, m = g >> 4, c4 = g & 15;
      ast[p] = *reinterpret_cast<const f32x4*>(Ag + (size_t)m * DIM_H + k0 + c4 * 4);
    }
    #pragma unroll
    for (int it = 0; it < 4; it++) {  // B tiles: 64(k)x64(n), gather 4 k per thread
      int ks = bkb + it * 16;
      #pragma unroll
      for (int i = 0; i < 4; i++) {
        bgst[it * 4 + i] = Bgg[(size_t)(k0 + ks + i) * DIM_F + bn];
        bust[it * 4 + i] = Bug[(size_t)(k0 + ks + i) * DIM_F + bn];
      }
    }
  };
  auto writeT = [&]() {
    #pragma unroll
    for (int p = 0; p < 8; p++) {
      int g = p * 256 + t, m = g >> 4, c4 = g & 15;
      int off = m * 128 + ((c4 * 8) ^ ((m & 7) << 4));           // swizzled
      *reinterpret_cast<uint2*>(&smem[off]) =
          make_uint2(bfpair(ast[p][0], ast[p][1]), bfpair(ast[p][2], ast[p][3]));
    }
    #pragma unroll
    for (int it = 0; it < 4; it++) {
      int ks = bkb + it * 16;
      int off = 16384 + bn * 128 + ((ks * 2) ^ ((bn & 7) << 4)); // B^T[n][k], swizzled
      *reinterpret_cast<uint2*>(&smem[off]) =
          make_uint2(bfpair(bgst[it*4+0], bgst[it*4+1]), bfpair(bgst[it*4+2], bgst[it*4+3]));
      *reinterpret_cast<uint2*>(&smem[off + 8192]) =
          make_uint2(bfpair(bust[it*4+0], bust[it*4+1]), bfpair(bust[it*4+2], bust[it*4+3]));
    }
  };
  auto compute = [&]() {
    #pragma unroll
    for (int kk = 0; kk < 2; kk++) {
      short8 a[4], bg[2], bu[2];
      #pragma unroll
      for (int mi = 0; mi < 4; mi++) {
        int row = wm * 64 + mi * 16 + (lane & 15);
        int off = row * 128 + ((kk * 64 + (lane >> 4) * 16) ^ ((row & 7) << 4));
        a[mi] = *reinterpret_cast<const short8*>(&smem[off]);
      }
      #pragma unroll
      for (int ni = 0; ni < 2; ni++) {
        int n = wn * 32 + ni * 16 + (lane & 15);
        int off = 16384 + n * 128 + ((kk * 64 + (lane >> 4) * 16) ^ ((n & 7) << 4));
        bg[ni] = *reinterpret_cast<const short8*>(&smem[off]);
        bu[ni] = *reinterpret_cast<const short8*>(&smem[off + 8192]);
      }
      #pragma unroll
      for (int mi = 0; mi < 4; mi++)
        #pragma unroll
        for (int ni = 0; ni < 2; ni++) {
          accg[mi][ni] = __builtin_amdgcn_mfma_f32_16x16x32_bf16(a[mi], bg[ni], accg[mi][ni], 0, 0, 0);
          accu[mi][ni] = __builtin_amdgcn_mfma_f32_16x16x32_bf16(a[mi], bu[ni], accu[mi][ni], 0, 0, 0);
        }
    }
  };

  loadT(0);
  writeT();
  __syncthreads();
  for (int kt = 0; kt < DIM_H / 64; kt++) {
    if (kt < DIM_H / 64 - 1) loadT((kt + 1) * 64);   // overlap next-tile loads
    compute();
    __syncthreads();
    if (kt < DIM_H / 64 - 1) { writeT(); __syncthreads(); }
  }

  // epilogue: silu(g)*u -> bf16. C/D layout: col=lane&15, row=(lane>>4)*4+j.
  #pragma unroll
  for (int mi = 0; mi < 4; mi++)
    #pragma unroll
    for (int ni = 0; ni < 2; ni++) {
      int col = col0 + wn * 32 + ni * 16 + (lane & 15);
      int rbase = row0 + wm * 64 + mi * 16 + ((lane >> 4) & 3) * 4;
      #pragma unroll
      for (int j = 0; j < 4; j++) {
        float g = accg[mi][ni][j], u = accu[mi][ni][j];
        float hv = (g / (1.f + __expf(-g))) * u;
        hout[(size_t)(rbase + j) * DIM_F + col] = f2bf(hv);
      }
    }
}

// ---------------- Kernel 2: out = h Wd, f32 out ----------------
// Tile: BM=128 x BN=128 x BK=64. 4 waves; wave tile 64x64.
__global__ __launch_bounds__(256, 2) void down_kernel(
    const unsigned short* __restrict__ hin, const float* __restrict__ wd,
    float* __restrict__ out)
{
  __shared__ unsigned char smem[32768]; // As[128][64]bf16 16KB | Bd^T[128][64] 16KB
  const int t = threadIdx.x;
  const int bid = blockIdx.x;
  const int e = bid >> 5, rr = bid & 31, mb = rr >> 3, nb = rr & 7;
  const int row0 = e * CAP + mb * 128;
  const int col0 = nb * 128;
  const unsigned short* Ag = hin + (size_t)row0 * DIM_F;
  const float* Bdg = wd + (size_t)e * DIM_F * DIM_H + col0;

  const int lane = t & 63, wid = t >> 6;
  const int wm = wid >> 1, wn = wid & 1;

  f32x4 acc[4][4];
  #pragma unroll
  for (int i = 0; i < 4; i++)
    #pragma unroll
    for (int j = 0; j < 4; j++) acc[i][j] = f32x4{0.f, 0.f, 0.f, 0.f};

  int4 ast[4];
  float bst[32];
  const int bn = t & 127, bkb = (t >> 7) * 4;

  auto loadT = [&](int k0) {
    #pragma unroll
    for (int p = 0; p < 4; p++) {     // A tile: 128x64 bf16, 8 threads/row (16B each)
      int g = p * 256 + t, m = g >> 3, c8 = g & 7;
      ast[p] = *reinterpret_cast<const int4*>(Ag + (size_t)m * DIM_F + k0 + c8 * 8);
    }
    #pragma unroll
    for (int it = 0; it < 8; it++) {  // B tile: 64(k)x128(n)
      int ks = bkb + it * 8;
      #pragma unroll
      for (int i = 0; i < 4; i++)
        bst[it * 4 + i] = Bdg[(size_t)(k0 + ks + i) * DIM_H + bn];
    }
  };
  auto writeT = [&]() {
    #pragma unroll
    for (int p = 0; p < 4; p++) {
      int g = p * 256 + t, m = g >> 3, c8 = g & 7;
      int off = m * 128 + ((c8 * 16) ^ ((m & 7) << 4));
      *reinterpret_cast<int4*>(&smem[off]) = ast[p];
    }
    #pragma unroll
    for (int it = 0; it < 8; it++) {
      int ks = bkb + it * 8;
      int off = 16384 + bn * 128 + ((ks * 2) ^ ((bn & 7) << 4));
      *reinterpret_cast<uint2*>(&smem[off]) =
          make_uint2(bfpair(bst[it*4+0], bst[it*4+1]), bfpair(bst[it*4+2], bst[it*4+3]));
    }
  };
  auto compute = [&]() {
    #pragma unroll
    for (int kk = 0; kk < 2; kk++) {
      short8 a[4], b[4];
      #pragma unroll
      for (int mi = 0; mi < 4; mi++) {
        int row = wm * 64 + mi * 16 + (lane & 15);
        int off = row * 128 + ((kk * 64 + (lane >> 4) * 16) ^ ((row & 7) << 4));
        a[mi] = *reinterpret_cast<const short8*>(&smem[off]);
      }
      #pragma unroll
      for (int ni = 0; ni < 4; ni++) {
        int n = wn * 64 + ni * 16 + (lane & 15);
        int off = 16384 + n * 128 + ((kk * 64 + (lane >> 4) * 16) ^ ((n & 7) << 4));
        b[ni] = *reinterpret_cast<const short8*>(&smem[off]);
      }
      #pragma unroll
      for (int mi = 0; mi < 4; mi++)
        #pragma unroll
        for (int ni = 0; ni < 4; ni++)
          acc[mi][ni] = __builtin_amdgcn_mfma_f32_16x16x32_bf16(a[mi], b[ni], acc[mi][ni], 0, 0, 0);
    }
  };

  loadT(0);
  writeT();
  __syncthreads();
  for (int kt = 0; kt < DIM_F / 64; kt++) {
    if (kt < DIM_F / 64 - 1) loadT((kt + 1) * 64);
    compute();
    __syncthreads();
    if (kt < DIM_F / 64 - 1) { writeT(); __syncthreads(); }
  }

  #pragma unroll
  for (int mi = 0; mi < 4; mi++)
    #pragma unroll
    for (int ni = 0; ni < 4; ni++) {
      int col = col0 + wn * 64 + ni * 16 + (lane & 15);
      int rbase = row0 + wm * 64 + mi * 16 + ((lane >> 4) & 3) * 4;
      #pragma unroll
      for (int j = 0; j < 4; j++)
        out[(size_t)(rbase + j) * DIM_H + col] = acc[mi][ni][j];
    }
}

extern "C" void kernel_launch(void* const* d_in, const int* in_sizes, int n_in,
                              void* d_out, int out_size, void* d_ws, size_t ws_size,
                              hipStream_t stream) {
  (void)in_sizes; (void)n_in; (void)out_size; (void)ws_size;
  const float* x  = (const float*)d_in[0];
  // d_in[1] = tokens_per_expert: equal-count setup (C=512 each), dispatch is static.
  const float* wg = (const float*)d_in[2];
  const float* wu = (const float*)d_in[3];
  const float* wd = (const float*)d_in[4];
  unsigned short* h = (unsigned short*)d_ws;   // N*F bf16 = 64 MiB scratch
  float* out = (float*)d_out;

  gateup_kernel<<<dim3(NUM_E * 4 * 16), dim3(256), 0, stream>>>(x, wg, wu, h);
  down_kernel<<<dim3(NUM_E * 4 * 8), dim3(256), 0, stream>>>(h, wd, out);
}

// Round 3
// 448.758 us; speedup vs baseline: 1.3662x; 1.3662x over previous
//
#include <hip/hip_runtime.h>
#include <stdint.h>

// SequentialMLP (grouped MoE LLaMA-MLP), MI355X gfx950.
// E=64 experts x C=512 tokens, H=F=1024, f32 in/out, bf16 MFMA compute.
// R3: fix R2 grid bug (gateup needs 64 tiles/expert -> 4096 blocks; R2 launched
//     2048 so half of h was never written). Keeps R2's structure:
//     v_cvt_pk_bf16_f32 for all f32->bf16, A-tiles via global_load_lds with
//     pre-swizzled SOURCE addrs (rule #21), fused gate+up block, XCD swizzle.

#define NUM_E 64
#define DIM_H 1024
#define DIM_F 1024
#define CAP   512

typedef short short8 __attribute__((ext_vector_type(8)));
typedef float f32x4 __attribute__((ext_vector_type(4)));

__device__ __forceinline__ uint32_t cvtpk(float lo, float hi) {
  uint32_t r;
  asm("v_cvt_pk_bf16_f32 %0, %1, %2" : "=v"(r) : "v"(lo), "v"(hi));
  return r;
}
__device__ __forceinline__ unsigned short f2bf(float a) {
  uint32_t ua = __builtin_bit_cast(uint32_t, a);
  ua += 0x7FFFu + ((ua >> 16) & 1u);
  return (unsigned short)(ua >> 16);
}
__device__ __forceinline__ void gload_lds16(const void* g, void* l) {
  __builtin_amdgcn_global_load_lds((const __attribute__((address_space(1))) uint32_t*)g,
                                   (__attribute__((address_space(3))) uint32_t*)l, 16, 0, 0);
}

// ---------------- Kernel 1: h = silu(x Wg) * (x Wu), bf16 out ----------------
// Block: 128 tokens x (64 gate + 64 up) cols, BK=64, 256 thr / 4 waves (2m x 2n).
// Grid: 64 experts x (4 m-tiles x 16 n-tiles) = 4096 blocks.
// LDS: A f32 [128 rows][256B] 32KB | Bg^T [64][128B] 8KB | Bu^T 8KB = 48KB.
__global__ __launch_bounds__(256, 2) void gateup_kernel(
    const float* __restrict__ x, const float* __restrict__ wg,
    const float* __restrict__ wu, unsigned short* __restrict__ hout)
{
  __shared__ unsigned char smem[49152];
  const int t = threadIdx.x;
  int bid = blockIdx.x;
  bid = (bid & 7) * 512 + (bid >> 3);          // XCD-bijective swizzle (4096 = 8*512)
  const int e = bid >> 6, rr = bid & 63, mb = rr >> 4, nb = rr & 15;
  const int row0 = e * CAP + mb * 128;
  const int col0 = nb * 64;
  const float* Ag  = x  + (size_t)row0 * DIM_H;
  const float* Bgg = wg + (size_t)e * (DIM_H * DIM_F) + col0;
  const float* Bug = wu + (size_t)e * (DIM_H * DIM_F) + col0;

  const int lane = t & 63, wid = t >> 6;
  const int wm = wid >> 1, wn = wid & 1;

  f32x4 acc[4][4];   // [mi][ni]: ni 0,1 = gate, 2,3 = up
  #pragma unroll
  for (int i = 0; i < 4; i++)
    #pragma unroll
    for (int j = 0; j < 4; j++) acc[i][j] = f32x4{0.f, 0.f, 0.f, 0.f};

  const int bn = t & 63, bkb = (t >> 6) * 4;
  float bg[16], bu[16];

  auto loadB = [&](int k0) {
    #pragma unroll
    for (int it = 0; it < 4; it++) {
      int ks = bkb + it * 16;
      #pragma unroll
      for (int i = 0; i < 4; i++) {
        bg[it*4+i] = Bgg[(size_t)(k0 + ks + i) * DIM_F + bn];
        bu[it*4+i] = Bug[(size_t)(k0 + ks + i) * DIM_F + bn];
      }
    }
  };
  auto writeB = [&]() {
    #pragma unroll
    for (int it = 0; it < 4; it++) {
      int ks = bkb + it * 16;
      int off = 32768 + bn * 128 + ((ks * 2) ^ ((bn & 7) << 4));
      *reinterpret_cast<uint2*>(&smem[off]) =
          make_uint2(cvtpk(bg[it*4+0], bg[it*4+1]), cvtpk(bg[it*4+2], bg[it*4+3]));
      *reinterpret_cast<uint2*>(&smem[off + 8192]) =
          make_uint2(cvtpk(bu[it*4+0], bu[it*4+1]), cvtpk(bu[it*4+2], bu[it*4+3]));
    }
  };
  // A tile: 128x64 f32 = 32KB, direct global->LDS, source pre-swizzled so that
  // LDS physical quad p of row r holds logical quad p^(r&7).
  auto loadA = [&](int k0) {
    #pragma unroll
    for (int j = 0; j < 8; j++) {
      int lin = (wid * 8 + j) * 1024 + lane * 16;
      int r = lin >> 8;              // row (256B per row)
      int q = (lin >> 4) & 15;       // 16B quad within row
      const void* src = (const unsigned char*)Ag + (size_t)r * 4096 + k0 * 4 + ((q ^ (r & 7)) * 16);
      gload_lds16(src, &smem[(wid * 8 + j) * 1024]);
    }
  };
  auto ldA = [&](int mi, int kk) -> short8 {
    int r = wm * 64 + mi * 16 + (lane & 15);
    int c = kk * 128 + (lane >> 4) * 32;
    int swz = (r & 7) << 4;
    f32x4 f0 = *reinterpret_cast<const f32x4*>(&smem[r * 256 + (c ^ swz)]);
    f32x4 f1 = *reinterpret_cast<const f32x4*>(&smem[r * 256 + ((c + 16) ^ swz)]);
    int4 ai = make_int4((int)cvtpk(f0[0], f0[1]), (int)cvtpk(f0[2], f0[3]),
                        (int)cvtpk(f1[0], f1[1]), (int)cvtpk(f1[2], f1[3]));
    return __builtin_bit_cast(short8, ai);
  };
  auto ldB = [&](int base, int n, int kk) -> short8 {
    int off = base + n * 128 + ((kk * 64 + (lane >> 4) * 16) ^ ((n & 7) << 4));
    return *reinterpret_cast<const short8*>(&smem[off]);
  };
  auto compute = [&]() {
    #pragma unroll
    for (int kk = 0; kk < 2; kk++) {
      short8 a[4], bgf[2], buf_[2];
      #pragma unroll
      for (int mi = 0; mi < 4; mi++) a[mi] = ldA(mi, kk);
      #pragma unroll
      for (int ni = 0; ni < 2; ni++) {
        int n = wn * 32 + ni * 16 + (lane & 15);
        bgf[ni]  = ldB(32768, n, kk);
        buf_[ni] = ldB(40960, n, kk);
      }
      #pragma unroll
      for (int mi = 0; mi < 4; mi++)
        #pragma unroll
        for (int ni = 0; ni < 2; ni++) {
          acc[mi][ni]     = __builtin_amdgcn_mfma_f32_16x16x32_bf16(a[mi], bgf[ni],  acc[mi][ni],     0, 0, 0);
          acc[mi][ni + 2] = __builtin_amdgcn_mfma_f32_16x16x32_bf16(a[mi], buf_[ni], acc[mi][ni + 2], 0, 0, 0);
        }
    }
  };

  loadB(0);
  loadA(0);
  writeB();
  __syncthreads();
  const int NT = DIM_H / 64;
  for (int kt = 0; kt < NT; kt++) {
    if (kt + 1 < NT) loadB((kt + 1) * 64);     // overlap next B loads with compute
    compute();
    __syncthreads();
    if (kt + 1 < NT) { loadA((kt + 1) * 64); writeB(); __syncthreads(); }
  }

  // epilogue: silu(g)*u -> bf16. C/D: col=lane&15, row=(lane>>4)*4+j.
  #pragma unroll
  for (int mi = 0; mi < 4; mi++)
    #pragma unroll
    for (int nc = 0; nc < 2; nc++) {
      int col = col0 + wn * 32 + nc * 16 + (lane & 15);
      int rbase = row0 + wm * 64 + mi * 16 + (lane >> 4) * 4;
      #pragma unroll
      for (int j = 0; j < 4; j++) {
        float g = acc[mi][nc][j], u = acc[mi][nc + 2][j];
        float hv = (g / (1.f + __expf(-g))) * u;
        hout[(size_t)(rbase + j) * DIM_F + col] = f2bf(hv);
      }
    }
}

// ---------------- Kernel 2: out = h Wd, f32 out ----------------
// Block: 128 x 128, BK=64, 256 thr / 4 waves (2m x 2n), wave 64x64.
// Grid: 64 experts x (4 m-tiles x 8 n-tiles) = 2048 blocks.
// LDS: A bf16 [128][128B] 16KB | Bd^T [128][128B] 16KB = 32KB.
__global__ __launch_bounds__(256, 2) void down_kernel(
    const unsigned short* __restrict__ hin, const float* __restrict__ wd,
    float* __restrict__ out)
{
  __shared__ unsigned char smem[32768];
  const int t = threadIdx.x;
  int bid = blockIdx.x;
  bid = (bid & 7) * 256 + (bid >> 3);          // XCD-bijective swizzle (2048 = 8*256)
  const int e = bid >> 5, rr = bid & 31, mb = rr >> 3, nb = rr & 7;
  const int row0 = e * CAP + mb * 128;
  const int col0 = nb * 128;
  const unsigned short* Ag = hin + (size_t)row0 * DIM_F;
  const float* Bdg = wd + (size_t)e * (DIM_F * DIM_H) + col0;

  const int lane = t & 63, wid = t >> 6;
  const int wm = wid >> 1, wn = wid & 1;

  f32x4 acc[4][4];
  #pragma unroll
  for (int i = 0; i < 4; i++)
    #pragma unroll
    for (int j = 0; j < 4; j++) acc[i][j] = f32x4{0.f, 0.f, 0.f, 0.f};

  const int bn = t & 127, bkb = (t >> 7) * 4;
  float bs[32];

  auto loadB = [&](int k0) {
    #pragma unroll
    for (int it = 0; it < 8; it++) {
      int ks = bkb + it * 8;
      #pragma unroll
      for (int i = 0; i < 4; i++)
        bs[it*4+i] = Bdg[(size_t)(k0 + ks + i) * DIM_H + bn];
    }
  };
  auto writeB = [&]() {
    #pragma unroll
    for (int it = 0; it < 8; it++) {
      int ks = bkb + it * 8;
      int off = 16384 + bn * 128 + ((ks * 2) ^ ((bn & 7) << 4));
      *reinterpret_cast<uint2*>(&smem[off]) =
          make_uint2(cvtpk(bs[it*4+0], bs[it*4+1]), cvtpk(bs[it*4+2], bs[it*4+3]));
    }
  };
  // A tile: 128x64 bf16 = 16KB via global_load_lds, pre-swizzled source.
  auto loadA = [&](int k0) {
    #pragma unroll
    for (int j = 0; j < 4; j++) {
      int lin = (wid * 4 + j) * 1024 + lane * 16;
      int r = lin >> 7;             // row (128B per row)
      int q = (lin >> 4) & 7;       // 16B quad
      const void* src = (const unsigned char*)Ag + (size_t)r * 2048 + k0 * 2 + ((q ^ (r & 7)) * 16);
      gload_lds16(src, &smem[(wid * 4 + j) * 1024]);
    }
  };
  auto ldA = [&](int mi, int kk) -> short8 {
    int r = wm * 64 + mi * 16 + (lane & 15);
    int off = r * 128 + ((kk * 64 + (lane >> 4) * 16) ^ ((r & 7) << 4));
    return *reinterpret_cast<const short8*>(&smem[off]);
  };
  auto ldB = [&](int ni, int kk) -> short8 {
    int n = wn * 64 + ni * 16 + (lane & 15);
    int off = 16384 + n * 128 + ((kk * 64 + (lane >> 4) * 16) ^ ((n & 7) << 4));
    return *reinterpret_cast<const short8*>(&smem[off]);
  };
  auto compute = [&]() {
    #pragma unroll
    for (int kk = 0; kk < 2; kk++) {
      short8 a[4], b[4];
      #pragma unroll
      for (int mi = 0; mi < 4; mi++) a[mi] = ldA(mi, kk);
      #pragma unroll
      for (int ni = 0; ni < 4; ni++) b[ni] = ldB(ni, kk);
      #pragma unroll
      for (int mi = 0; mi < 4; mi++)
        #pragma unroll
        for (int ni = 0; ni < 4; ni++)
          acc[mi][ni] = __builtin_amdgcn_mfma_f32_16x16x32_bf16(a[mi], b[ni], acc[mi][ni], 0, 0, 0);
    }
  };

  loadB(0);
  loadA(0);
  writeB();
  __syncthreads();
  const int NT = DIM_F / 64;
  for (int kt = 0; kt < NT; kt++) {
    if (kt + 1 < NT) loadB((kt + 1) * 64);
    compute();
    __syncthreads();
    if (kt + 1 < NT) { loadA((kt + 1) * 64); writeB(); __syncthreads(); }
  }

  #pragma unroll
  for (int mi = 0; mi < 4; mi++)
    #pragma unroll
    for (int ni = 0; ni < 4; ni++) {
      int col = col0 + wn * 64 + ni * 16 + (lane & 15);
      int rbase = row0 + wm * 64 + mi * 16 + (lane >> 4) * 4;
      #pragma unroll
      for (int j = 0; j < 4; j++)
        out[(size_t)(rbase + j) * DIM_H + col] = acc[mi][ni][j];
    }
}

extern "C" void kernel_launch(void* const* d_in, const int* in_sizes, int n_in,
                              void* d_out, int out_size, void* d_ws, size_t ws_size,
                              hipStream_t stream) {
  (void)in_sizes; (void)n_in; (void)out_size; (void)ws_size;
  const float* x  = (const float*)d_in[0];
  // d_in[1] = tokens_per_expert: equal-count setup (C=512 each), static dispatch.
  const float* wg = (const float*)d_in[2];
  const float* wu = (const float*)d_in[3];
  const float* wd = (const float*)d_in[4];
  unsigned short* h = (unsigned short*)d_ws;   // N*F bf16 = 64 MiB scratch
  float* out = (float*)d_out;

  gateup_kernel<<<dim3(4096), dim3(256), 0, stream>>>(x, wg, wu, h);
  down_kernel<<<dim3(2048), dim3(256), 0, stream>>>(h, wd, out);
}

// Round 4
// 426.651 us; speedup vs baseline: 1.4370x; 1.0518x over previous
//
#include <hip/hip_runtime.h>
#include <stdint.h>

// SequentialMLP (grouped MoE LLaMA-MLP), MI355X gfx950.
// E=64 experts x C=512 tokens, H=F=1024, f32 in/out, bf16 MFMA compute.
// R4: pipelined 1-barrier/K-tile loop (T3/T4-min): A triple-buffered via
//     global_load_lds issued 2 tiles ahead, B double-buffered reg-staged,
//     counted vmcnt (never 0 mid-loop), raw s_barrier + lgkmcnt(0) +
//     sched_barrier(0). x converted to bf16 once (ws-guarded; R3 gateup kept
//     as fallback). T5 setprio around MFMA cluster.

#define NUM_E 64
#define DIM_H 1024
#define DIM_F 1024
#define CAP   512
#define NTOK  32768

typedef short short8 __attribute__((ext_vector_type(8)));
typedef float f32x4 __attribute__((ext_vector_type(4)));

#define VMCNT(n)  asm volatile("s_waitcnt vmcnt(" #n ")" ::: "memory")
#define LGKMCNT0  asm volatile("s_waitcnt lgkmcnt(0)" ::: "memory")
#define SBAR      __builtin_amdgcn_s_barrier()
#define SCHED0    __builtin_amdgcn_sched_barrier(0)

__device__ __forceinline__ uint32_t cvtpk(float lo, float hi) {
  uint32_t r;
  asm("v_cvt_pk_bf16_f32 %0, %1, %2" : "=v"(r) : "v"(lo), "v"(hi));
  return r;
}
__device__ __forceinline__ unsigned short f2bf(float a) {
  uint32_t ua = __builtin_bit_cast(uint32_t, a);
  ua += 0x7FFFu + ((ua >> 16) & 1u);
  return (unsigned short)(ua >> 16);
}
__device__ __forceinline__ void gload_lds16(const void* g, void* l) {
  __builtin_amdgcn_global_load_lds((const __attribute__((address_space(1))) uint32_t*)g,
                                   (__attribute__((address_space(3))) uint32_t*)l, 16, 0, 0);
}

// ---------------- Kernel 0: x f32 -> bf16 ----------------
__global__ __launch_bounds__(256) void cvt_kernel(const float* __restrict__ x,
                                                  unsigned short* __restrict__ xbf) {
  size_t i = ((size_t)blockIdx.x * 256 + threadIdx.x) * 8;
  f32x4 a = *reinterpret_cast<const f32x4*>(x + i);
  f32x4 b = *reinterpret_cast<const f32x4*>(x + i + 4);
  int4 o = make_int4((int)cvtpk(a[0], a[1]), (int)cvtpk(a[2], a[3]),
                     (int)cvtpk(b[0], b[1]), (int)cvtpk(b[2], b[3]));
  *reinterpret_cast<int4*>(xbf + i) = o;
}

// ---------------- Kernel 1 (fast): h = silu(x Wg)*(x Wu), bf16 in/out -------
// Block 128m x (64g+64u) cols, BK=64, 256 thr / 4 waves (2m x 2n). Grid 4096.
// LDS 80KB: A bf16 3x16KB @0; B bufs @49152: {Bg 8KB, Bu 8KB} x2.
__global__ __launch_bounds__(256, 2) void gateup_kernel_bf(
    const unsigned short* __restrict__ xbf, const float* __restrict__ wg,
    const float* __restrict__ wu, unsigned short* __restrict__ hout)
{
  __shared__ unsigned char smem[81920];
  const int t = threadIdx.x;
  int bid = blockIdx.x;
  bid = (bid & 7) * 512 + (bid >> 3);          // XCD-bijective (4096 = 8*512)
  const int e = bid >> 6, rr = bid & 63, mb = rr >> 4, nb = rr & 15;
  const int row0 = e * CAP + mb * 128;
  const int col0 = nb * 64;
  const unsigned short* Ag = xbf + (size_t)row0 * DIM_H;
  const float* Bgg = wg + (size_t)e * (DIM_H * DIM_F) + col0;
  const float* Bug = wu + (size_t)e * (DIM_H * DIM_F) + col0;

  const int lane = t & 63, wid = t >> 6;
  const int wm = wid >> 1, wn = wid & 1;

  f32x4 acc[4][4];   // ni 0,1 = gate; 2,3 = up
  #pragma unroll
  for (int i = 0; i < 4; i++)
    #pragma unroll
    for (int j = 0; j < 4; j++) acc[i][j] = f32x4{0.f, 0.f, 0.f, 0.f};

  const int bn = t & 63, bkb = (t >> 6) * 4;
  float bg[16], bu[16];

  auto loadB = [&](int k0) {
    #pragma unroll
    for (int it = 0; it < 4; it++) {
      int ks = bkb + it * 16;
      #pragma unroll
      for (int i = 0; i < 4; i++) {
        bg[it*4+i] = Bgg[(size_t)(k0 + ks + i) * DIM_F + bn];
        bu[it*4+i] = Bug[(size_t)(k0 + ks + i) * DIM_F + bn];
      }
    }
  };
  auto writeB = [&](int b) {
    const int Bb = 49152 + b * 16384;
    #pragma unroll
    for (int it = 0; it < 4; it++) {
      int ks = bkb + it * 16;
      int off = Bb + bn * 128 + ((ks * 2) ^ ((bn & 7) << 4));
      *reinterpret_cast<uint2*>(&smem[off]) =
          make_uint2(cvtpk(bg[it*4+0], bg[it*4+1]), cvtpk(bg[it*4+2], bg[it*4+3]));
      *reinterpret_cast<uint2*>(&smem[off + 8192]) =
          make_uint2(cvtpk(bu[it*4+0], bu[it*4+1]), cvtpk(bu[it*4+2], bu[it*4+3]));
    }
  };
  // A tile 128x64 bf16 = 16KB via global_load_lds; linear LDS dest, source
  // pre-swizzled (quad q of row r holds logical quad q^(r&7)).
  auto loadA = [&](int k0, int buf) {
    #pragma unroll
    for (int j = 0; j < 4; j++) {
      int lin = (wid * 4 + j) * 1024 + lane * 16;
      int r = lin >> 7;             // 128B per row
      int q = (lin >> 4) & 7;
      const void* src = (const unsigned char*)Ag + (size_t)r * 2048 + k0 * 2 + ((q ^ (r & 7)) * 16);
      gload_lds16(src, &smem[buf * 16384 + (wid * 4 + j) * 1024]);
    }
  };
  auto compute = [&](int kt) {
    const int Ab = (kt % 3) * 16384;
    const int Bb = 49152 + (kt & 1) * 16384;
    __builtin_amdgcn_s_setprio(1);
    #pragma unroll
    for (int kk = 0; kk < 2; kk++) {
      short8 a[4], bgf[2], buf_[2];
      #pragma unroll
      for (int mi = 0; mi < 4; mi++) {
        int r = wm * 64 + mi * 16 + (lane & 15);
        a[mi] = *reinterpret_cast<const short8*>(
            &smem[Ab + r * 128 + ((kk * 64 + (lane >> 4) * 16) ^ ((r & 7) << 4))]);
      }
      #pragma unroll
      for (int ni = 0; ni < 2; ni++) {
        int n = wn * 32 + ni * 16 + (lane & 15);
        int off = Bb + n * 128 + ((kk * 64 + (lane >> 4) * 16) ^ ((n & 7) << 4));
        bgf[ni]  = *reinterpret_cast<const short8*>(&smem[off]);
        buf_[ni] = *reinterpret_cast<const short8*>(&smem[off + 8192]);
      }
      #pragma unroll
      for (int mi = 0; mi < 4; mi++)
        #pragma unroll
        for (int ni = 0; ni < 2; ni++) {
          acc[mi][ni]     = __builtin_amdgcn_mfma_f32_16x16x32_bf16(a[mi], bgf[ni],  acc[mi][ni],     0, 0, 0);
          acc[mi][ni + 2] = __builtin_amdgcn_mfma_f32_16x16x32_bf16(a[mi], buf_[ni], acc[mi][ni + 2], 0, 0, 0);
        }
    }
    __builtin_amdgcn_s_setprio(0);
  };

  const int NT = DIM_H / 64;   // 16
  // prologue: issue scalars B(0)[32], A(0)[4], A(1)[4]
  loadB(0);
  loadA(0, 0);
  loadA(64, 1);
  SCHED0;
  VMCNT(8);          // B(0) scalars done; A(0),A(1) in flight
  SCHED0;
  writeB(0);
  VMCNT(4);          // A(0) done; A(1) in flight
  LGKMCNT0;
  SCHED0;
  SBAR;
  for (int kt = 0; kt < NT; kt++) {
    if (kt + 1 < NT) {
      loadB((kt + 1) * 64);
      if (kt + 2 < NT) loadA((kt + 2) * 64, (kt + 2) % 3);
      SCHED0;
    }
    compute(kt);
    if (kt + 1 < NT) {
      if (kt + 2 < NT) { VMCNT(4); } else { VMCNT(0); }   // scalars(t+1)+A(t+1) done
      SCHED0;
      writeB((kt + 1) & 1);
      LGKMCNT0;
      SCHED0;
      SBAR;
    }
  }

  // epilogue: silu(g)*u -> bf16. C/D: col=lane&15, row=(lane>>4)*4+j.
  #pragma unroll
  for (int mi = 0; mi < 4; mi++)
    #pragma unroll
    for (int nc = 0; nc < 2; nc++) {
      int col = col0 + wn * 32 + nc * 16 + (lane & 15);
      int rbase = row0 + wm * 64 + mi * 16 + (lane >> 4) * 4;
      #pragma unroll
      for (int j = 0; j < 4; j++) {
        float g = acc[mi][nc][j], u = acc[mi][nc + 2][j];
        float hv = (g / (1.f + __expf(-g))) * u;
        hout[(size_t)(rbase + j) * DIM_F + col] = f2bf(hv);
      }
    }
}

// ---------------- Kernel 1 (fallback, R3-proven): reads x f32 ----------------
__global__ __launch_bounds__(256, 2) void gateup_kernel(
    const float* __restrict__ x, const float* __restrict__ wg,
    const float* __restrict__ wu, unsigned short* __restrict__ hout)
{
  __shared__ unsigned char smem[49152];
  const int t = threadIdx.x;
  int bid = blockIdx.x;
  bid = (bid & 7) * 512 + (bid >> 3);
  const int e = bid >> 6, rr = bid & 63, mb = rr >> 4, nb = rr & 15;
  const int row0 = e * CAP + mb * 128;
  const int col0 = nb * 64;
  const float* Ag  = x  + (size_t)row0 * DIM_H;
  const float* Bgg = wg + (size_t)e * (DIM_H * DIM_F) + col0;
  const float* Bug = wu + (size_t)e * (DIM_H * DIM_F) + col0;
  const int lane = t & 63, wid = t >> 6;
  const int wm = wid >> 1, wn = wid & 1;
  f32x4 acc[4][4];
  #pragma unroll
  for (int i = 0; i < 4; i++)
    #pragma unroll
    for (int j = 0; j < 4; j++) acc[i][j] = f32x4{0.f, 0.f, 0.f, 0.f};
  const int bn = t & 63, bkb = (t >> 6) * 4;
  float bg[16], bu[16];
  auto loadB = [&](int k0) {
    #pragma unroll
    for (int it = 0; it < 4; it++) {
      int ks = bkb + it * 16;
      #pragma unroll
      for (int i = 0; i < 4; i++) {
        bg[it*4+i] = Bgg[(size_t)(k0 + ks + i) * DIM_F + bn];
        bu[it*4+i] = Bug[(size_t)(k0 + ks + i) * DIM_F + bn];
      }
    }
  };
  auto writeB = [&]() {
    #pragma unroll
    for (int it = 0; it < 4; it++) {
      int ks = bkb + it * 16;
      int off = 32768 + bn * 128 + ((ks * 2) ^ ((bn & 7) << 4));
      *reinterpret_cast<uint2*>(&smem[off]) =
          make_uint2(cvtpk(bg[it*4+0], bg[it*4+1]), cvtpk(bg[it*4+2], bg[it*4+3]));
      *reinterpret_cast<uint2*>(&smem[off + 8192]) =
          make_uint2(cvtpk(bu[it*4+0], bu[it*4+1]), cvtpk(bu[it*4+2], bu[it*4+3]));
    }
  };
  auto loadA = [&](int k0) {
    #pragma unroll
    for (int j = 0; j < 8; j++) {
      int lin = (wid * 8 + j) * 1024 + lane * 16;
      int r = lin >> 8;
      int q = (lin >> 4) & 15;
      const void* src = (const unsigned char*)Ag + (size_t)r * 4096 + k0 * 4 + ((q ^ (r & 7)) * 16);
      gload_lds16(src, &smem[(wid * 8 + j) * 1024]);
    }
  };
  auto ldA = [&](int mi, int kk) -> short8 {
    int r = wm * 64 + mi * 16 + (lane & 15);
    int c = kk * 128 + (lane >> 4) * 32;
    int swz = (r & 7) << 4;
    f32x4 f0 = *reinterpret_cast<const f32x4*>(&smem[r * 256 + (c ^ swz)]);
    f32x4 f1 = *reinterpret_cast<const f32x4*>(&smem[r * 256 + ((c + 16) ^ swz)]);
    int4 ai = make_int4((int)cvtpk(f0[0], f0[1]), (int)cvtpk(f0[2], f0[3]),
                        (int)cvtpk(f1[0], f1[1]), (int)cvtpk(f1[2], f1[3]));
    return __builtin_bit_cast(short8, ai);
  };
  auto ldB = [&](int base, int n, int kk) -> short8 {
    int off = base + n * 128 + ((kk * 64 + (lane >> 4) * 16) ^ ((n & 7) << 4));
    return *reinterpret_cast<const short8*>(&smem[off]);
  };
  auto compute = [&]() {
    #pragma unroll
    for (int kk = 0; kk < 2; kk++) {
      short8 a[4], bgf[2], buf_[2];
      #pragma unroll
      for (int mi = 0; mi < 4; mi++) a[mi] = ldA(mi, kk);
      #pragma unroll
      for (int ni = 0; ni < 2; ni++) {
        int n = wn * 32 + ni * 16 + (lane & 15);
        bgf[ni]  = ldB(32768, n, kk);
        buf_[ni] = ldB(40960, n, kk);
      }
      #pragma unroll
      for (int mi = 0; mi < 4; mi++)
        #pragma unroll
        for (int ni = 0; ni < 2; ni++) {
          acc[mi][ni]     = __builtin_amdgcn_mfma_f32_16x16x32_bf16(a[mi], bgf[ni],  acc[mi][ni],     0, 0, 0);
          acc[mi][ni + 2] = __builtin_amdgcn_mfma_f32_16x16x32_bf16(a[mi], buf_[ni], acc[mi][ni + 2], 0, 0, 0);
        }
    }
  };
  loadB(0);
  loadA(0);
  writeB();
  __syncthreads();
  const int NT = DIM_H / 64;
  for (int kt = 0; kt < NT; kt++) {
    if (kt + 1 < NT) loadB((kt + 1) * 64);
    compute();
    __syncthreads();
    if (kt + 1 < NT) { loadA((kt + 1) * 64); writeB(); __syncthreads(); }
  }
  #pragma unroll
  for (int mi = 0; mi < 4; mi++)
    #pragma unroll
    for (int nc = 0; nc < 2; nc++) {
      int col = col0 + wn * 32 + nc * 16 + (lane & 15);
      int rbase = row0 + wm * 64 + mi * 16 + (lane >> 4) * 4;
      #pragma unroll
      for (int j = 0; j < 4; j++) {
        float g = acc[mi][nc][j], u = acc[mi][nc + 2][j];
        float hv = (g / (1.f + __expf(-g))) * u;
        hout[(size_t)(rbase + j) * DIM_F + col] = f2bf(hv);
      }
    }
}

// ---------------- Kernel 2: out = h Wd, f32 out (pipelined) ----------------
// Block 128x128, BK=64, 256 thr / 4 waves. Grid 2048.
// LDS 80KB: A bf16 3x16KB @0; Bd 2x16KB @49152.
__global__ __launch_bounds__(256, 2) void down_kernel(
    const unsigned short* __restrict__ hin, const float* __restrict__ wd,
    float* __restrict__ out)
{
  __shared__ unsigned char smem[81920];
  const int t = threadIdx.x;
  int bid = blockIdx.x;
  bid = (bid & 7) * 256 + (bid >> 3);          // XCD-bijective (2048 = 8*256)
  const int e = bid >> 5, rr = bid & 31, mb = rr >> 3, nb = rr & 7;
  const int row0 = e * CAP + mb * 128;
  const int col0 = nb * 128;
  const unsigned short* Ag = hin + (size_t)row0 * DIM_F;
  const float* Bdg = wd + (size_t)e * (DIM_F * DIM_H) + col0;

  const int lane = t & 63, wid = t >> 6;
  const int wm = wid >> 1, wn = wid & 1;

  f32x4 acc[4][4];
  #pragma unroll
  for (int i = 0; i < 4; i++)
    #pragma unroll
    for (int j = 0; j < 4; j++) acc[i][j] = f32x4{0.f, 0.f, 0.f, 0.f};

  const int bn = t & 127, bkb = (t >> 7) * 4;
  float bs[32];

  auto loadB = [&](int k0) {
    #pragma unroll
    for (int it = 0; it < 8; it++) {
      int ks = bkb + it * 8;
      #pragma unroll
      for (int i = 0; i < 4; i++)
        bs[it*4+i] = Bdg[(size_t)(k0 + ks + i) * DIM_H + bn];
    }
  };
  auto writeB = [&](int b) {
    const int Bb = 49152 + b * 16384;
    #pragma unroll
    for (int it = 0; it < 8; it++) {
      int ks = bkb + it * 8;
      int off = Bb + bn * 128 + ((ks * 2) ^ ((bn & 7) << 4));
      *reinterpret_cast<uint2*>(&smem[off]) =
          make_uint2(cvtpk(bs[it*4+0], bs[it*4+1]), cvtpk(bs[it*4+2], bs[it*4+3]));
    }
  };
  auto loadA = [&](int k0, int buf) {
    #pragma unroll
    for (int j = 0; j < 4; j++) {
      int lin = (wid * 4 + j) * 1024 + lane * 16;
      int r = lin >> 7;
      int q = (lin >> 4) & 7;
      const void* src = (const unsigned char*)Ag + (size_t)r * 2048 + k0 * 2 + ((q ^ (r & 7)) * 16);
      gload_lds16(src, &smem[buf * 16384 + (wid * 4 + j) * 1024]);
    }
  };
  auto compute = [&](int kt) {
    const int Ab = (kt % 3) * 16384;
    const int Bb = 49152 + (kt & 1) * 16384;
    __builtin_amdgcn_s_setprio(1);
    #pragma unroll
    for (int kk = 0; kk < 2; kk++) {
      short8 a[4], b[4];
      #pragma unroll
      for (int mi = 0; mi < 4; mi++) {
        int r = wm * 64 + mi * 16 + (lane & 15);
        a[mi] = *reinterpret_cast<const short8*>(
            &smem[Ab + r * 128 + ((kk * 64 + (lane >> 4) * 16) ^ ((r & 7) << 4))]);
      }
      #pragma unroll
      for (int ni = 0; ni < 4; ni++) {
        int n = wn * 64 + ni * 16 + (lane & 15);
        b[ni] = *reinterpret_cast<const short8*>(
            &smem[Bb + n * 128 + ((kk * 64 + (lane >> 4) * 16) ^ ((n & 7) << 4))]);
      }
      #pragma unroll
      for (int mi = 0; mi < 4; mi++)
        #pragma unroll
        for (int ni = 0; ni < 4; ni++)
          acc[mi][ni] = __builtin_amdgcn_mfma_f32_16x16x32_bf16(a[mi], b[ni], acc[mi][ni], 0, 0, 0);
    }
    __builtin_amdgcn_s_setprio(0);
  };

  const int NT = DIM_F / 64;   // 16
  loadB(0);
  loadA(0, 0);
  loadA(64, 1);
  SCHED0;
  VMCNT(8);
  SCHED0;
  writeB(0);
  VMCNT(4);
  LGKMCNT0;
  SCHED0;
  SBAR;
  for (int kt = 0; kt < NT; kt++) {
    if (kt + 1 < NT) {
      loadB((kt + 1) * 64);
      if (kt + 2 < NT) loadA((kt + 2) * 64, (kt + 2) % 3);
      SCHED0;
    }
    compute(kt);
    if (kt + 1 < NT) {
      if (kt + 2 < NT) { VMCNT(4); } else { VMCNT(0); }
      SCHED0;
      writeB((kt + 1) & 1);
      LGKMCNT0;
      SCHED0;
      SBAR;
    }
  }

  #pragma unroll
  for (int mi = 0; mi < 4; mi++)
    #pragma unroll
    for (int ni = 0; ni < 4; ni++) {
      int col = col0 + wn * 64 + ni * 16 + (lane & 15);
      int rbase = row0 + wm * 64 + mi * 16 + (lane >> 4) * 4;
      #pragma unroll
      for (int j = 0; j < 4; j++)
        out[(size_t)(rbase + j) * DIM_H + col] = acc[mi][ni][j];
    }
}

extern "C" void kernel_launch(void* const* d_in, const int* in_sizes, int n_in,
                              void* d_out, int out_size, void* d_ws, size_t ws_size,
                              hipStream_t stream) {
  (void)in_sizes; (void)n_in; (void)out_size;
  const float* x  = (const float*)d_in[0];
  // d_in[1] = tokens_per_expert: equal-count setup (C=512 each), static dispatch.
  const float* wg = (const float*)d_in[2];
  const float* wu = (const float*)d_in[3];
  const float* wd = (const float*)d_in[4];
  unsigned short* h = (unsigned short*)d_ws;                       // 64 MiB
  const size_t h_bytes = (size_t)NTOK * DIM_F * 2;
  float* out = (float*)d_out;

  if (ws_size >= h_bytes + (size_t)NTOK * DIM_H * 2) {
    unsigned short* xbf = (unsigned short*)((char*)d_ws + h_bytes); // 64 MiB
    cvt_kernel<<<dim3((NTOK * DIM_H) / (256 * 8)), dim3(256), 0, stream>>>(x, xbf);
    gateup_kernel_bf<<<dim3(4096), dim3(256), 0, stream>>>(xbf, wg, wu, h);
  } else {
    gateup_kernel<<<dim3(4096), dim3(256), 0, stream>>>(x, wg, wu, h);
  }
  down_kernel<<<dim3(2048), dim3(256), 0, stream>>>(h, wd, out);
}

// Round 5
// 365.234 us; speedup vs baseline: 1.6787x; 1.1682x over previous
//
#include <hip/hip_runtime.h>
#include <stdint.h>

// SequentialMLP (grouped MoE LLaMA-MLP), MI355X gfx950.
// E=64 experts x C=512 tokens, H=F=1024, f32 in/out, bf16 MFMA compute.
// R5: fat blocks to amortize B-staging (issue-bound per R4 counters):
//     256m x 128n(per matrix) blocks, 512 thr / 8 waves (4m x 2n), wave tile
//     64x64 per matrix -> 64 MFMA per K-tile per wave vs same 32 B-scalar
//     loads per thread. Both A and B double-buffered, 1 barrier/K-tile,
//     counted vmcnt, T5 setprio. cvt kernel (x->bf16) retained.

#define NUM_E 64
#define DIM_H 1024
#define DIM_F 1024
#define CAP   512
#define NTOK  32768

typedef short short8 __attribute__((ext_vector_type(8)));
typedef float f32x4 __attribute__((ext_vector_type(4)));

#define VMCNT(n)  asm volatile("s_waitcnt vmcnt(" #n ")" ::: "memory")
#define LGKMCNT0  asm volatile("s_waitcnt lgkmcnt(0)" ::: "memory")
#define SBAR      __builtin_amdgcn_s_barrier()
#define SCHED0    __builtin_amdgcn_sched_barrier(0)

__device__ __forceinline__ uint32_t cvtpk(float lo, float hi) {
  uint32_t r;
  asm("v_cvt_pk_bf16_f32 %0, %1, %2" : "=v"(r) : "v"(lo), "v"(hi));
  return r;
}
__device__ __forceinline__ unsigned short f2bf(float a) {
  uint32_t ua = __builtin_bit_cast(uint32_t, a);
  ua += 0x7FFFu + ((ua >> 16) & 1u);
  return (unsigned short)(ua >> 16);
}
__device__ __forceinline__ void gload_lds16(const void* g, void* l) {
  __builtin_amdgcn_global_load_lds((const __attribute__((address_space(1))) uint32_t*)g,
                                   (__attribute__((address_space(3))) uint32_t*)l, 16, 0, 0);
}

// ---------------- Kernel 0: x f32 -> bf16 ----------------
__global__ __launch_bounds__(256) void cvt_kernel(const float* __restrict__ x,
                                                  unsigned short* __restrict__ xbf) {
  size_t i = ((size_t)blockIdx.x * 256 + threadIdx.x) * 8;
  f32x4 a = *reinterpret_cast<const f32x4*>(x + i);
  f32x4 b = *reinterpret_cast<const f32x4*>(x + i + 4);
  int4 o = make_int4((int)cvtpk(a[0], a[1]), (int)cvtpk(a[2], a[3]),
                     (int)cvtpk(b[0], b[1]), (int)cvtpk(b[2], b[3]));
  *reinterpret_cast<int4*>(xbf + i) = o;
}

// ------ Kernel 1: h = silu(x Wg)*(x Wu), bf16 in/out.  256m x (128g+128u) ------
// 512 thr / 8 waves (4m x 2n). Grid 64e x 2mb x 8nb = 1024.
// LDS 128KB: A bf16 [256][128B] 2x32KB @0; B @65536 2x{Bg^T 16KB, Bu^T 16KB}.
__global__ __launch_bounds__(512, 2) void gateup_kernel_v3(
    const unsigned short* __restrict__ xbf, const float* __restrict__ wg,
    const float* __restrict__ wu, unsigned short* __restrict__ hout)
{
  __shared__ unsigned char smem[131072];
  const int t = threadIdx.x;
  int bid = blockIdx.x;
  bid = (bid & 7) * 128 + (bid >> 3);          // XCD-bijective (1024 = 8*128)
  const int e = bid >> 4, rr = bid & 15, mb = rr >> 3, nb = rr & 7;
  const int row0 = e * CAP + mb * 256;
  const int col0 = nb * 128;
  const unsigned short* Ag = xbf + (size_t)row0 * DIM_H;
  const float* Bgg = wg + (size_t)e * (DIM_H * DIM_F) + col0;
  const float* Bug = wu + (size_t)e * (DIM_H * DIM_F) + col0;

  const int lane = t & 63, wid = t >> 6;
  const int wm = wid >> 1, wn = wid & 1;       // 4m x 2n waves, wave 64m x 64n/matrix

  f32x4 accg[4][4], accu[4][4];
  #pragma unroll
  for (int i = 0; i < 4; i++)
    #pragma unroll
    for (int j = 0; j < 4; j++) {
      accg[i][j] = f32x4{0.f, 0.f, 0.f, 0.f};
      accu[i][j] = f32x4{0.f, 0.f, 0.f, 0.f};
    }

  const int bn = t & 127, bkb = (t >> 7) * 16;   // 4 k-groups of 16
  float bg[16], bu[16];

  auto loadB = [&](int k0) {
    #pragma unroll
    for (int i = 0; i < 16; i++) {
      bg[i] = Bgg[(size_t)(k0 + bkb + i) * DIM_F + bn];
      bu[i] = Bug[(size_t)(k0 + bkb + i) * DIM_F + bn];
    }
  };
  auto writeB = [&](int b) {
    const int Bb = 65536 + b * 32768;
    #pragma unroll
    for (int j = 0; j < 4; j++) {
      int off = Bb + bn * 128 + (((bkb + j * 4) * 2) ^ ((bn & 7) << 4));
      *reinterpret_cast<uint2*>(&smem[off]) =
          make_uint2(cvtpk(bg[j*4+0], bg[j*4+1]), cvtpk(bg[j*4+2], bg[j*4+3]));
      *reinterpret_cast<uint2*>(&smem[off + 16384]) =
          make_uint2(cvtpk(bu[j*4+0], bu[j*4+1]), cvtpk(bu[j*4+2], bu[j*4+3]));
    }
  };
  // A tile 256x64 bf16 = 32KB via global_load_lds; linear dest, pre-swizzled src.
  auto loadA = [&](int k0, int buf) {
    #pragma unroll
    for (int j = 0; j < 4; j++) {
      int lin = (j * 512 + t) * 16;
      int r = lin >> 7;             // 128B per row
      int q = (lin >> 4) & 7;
      const void* src = (const unsigned char*)Ag + (size_t)r * 2048 + k0 * 2 + ((q ^ (r & 7)) * 16);
      gload_lds16(src, &smem[buf * 32768 + lin]);
    }
  };
  auto compute = [&](int kt) {
    const int Ab = (kt & 1) * 32768;
    const int Bb = 65536 + (kt & 1) * 32768;
    __builtin_amdgcn_s_setprio(1);
    #pragma unroll
    for (int kk = 0; kk < 2; kk++) {
      short8 a[4], bgf[4], buf_[4];
      #pragma unroll
      for (int mi = 0; mi < 4; mi++) {
        int r = wm * 64 + mi * 16 + (lane & 15);
        a[mi] = *reinterpret_cast<const short8*>(
            &smem[Ab + r * 128 + ((kk * 64 + (lane >> 4) * 16) ^ ((r & 7) << 4))]);
      }
      #pragma unroll
      for (int ni = 0; ni < 4; ni++) {
        int n = wn * 64 + ni * 16 + (lane & 15);
        int off = Bb + n * 128 + ((kk * 64 + (lane >> 4) * 16) ^ ((n & 7) << 4));
        bgf[ni]  = *reinterpret_cast<const short8*>(&smem[off]);
        buf_[ni] = *reinterpret_cast<const short8*>(&smem[off + 16384]);
      }
      #pragma unroll
      for (int mi = 0; mi < 4; mi++)
        #pragma unroll
        for (int ni = 0; ni < 4; ni++) {
          accg[mi][ni] = __builtin_amdgcn_mfma_f32_16x16x32_bf16(a[mi], bgf[ni],  accg[mi][ni], 0, 0, 0);
          accu[mi][ni] = __builtin_amdgcn_mfma_f32_16x16x32_bf16(a[mi], buf_[ni], accu[mi][ni], 0, 0, 0);
        }
    }
    __builtin_amdgcn_s_setprio(0);
  };

  const int NT = DIM_H / 64;   // 16
  loadB(0);
  loadA(0, 0);
  VMCNT(4); SCHED0;            // 32 B scalars done; 4 A gloads in flight
  writeB(0);
  LGKMCNT0; VMCNT(0); SCHED0;
  SBAR;
  for (int kt = 0; kt < NT; kt++) {
    if (kt + 1 < NT) {
      loadB((kt + 1) * 64);
      loadA((kt + 1) * 64, (kt + 1) & 1);
      SCHED0;
    }
    compute(kt);
    if (kt + 1 < NT) {
      VMCNT(4); SCHED0;        // B(t+1) done; A(t+1) gloads in flight
      writeB((kt + 1) & 1);
      LGKMCNT0; VMCNT(0); SCHED0;
      SBAR;
    }
  }

  // epilogue: silu(g)*u -> bf16. C/D: col=lane&15, row=(lane>>4)*4+j.
  #pragma unroll
  for (int mi = 0; mi < 4; mi++)
    #pragma unroll
    for (int ni = 0; ni < 4; ni++) {
      int col = col0 + wn * 64 + ni * 16 + (lane & 15);
      int rbase = row0 + wm * 64 + mi * 16 + (lane >> 4) * 4;
      #pragma unroll
      for (int j = 0; j < 4; j++) {
        float g = accg[mi][ni][j], u = accu[mi][ni][j];
        float hv = (g / (1.f + __expf(-g))) * u;
        hout[(size_t)(rbase + j) * DIM_F + col] = f2bf(hv);
      }
    }
}

// ---------------- Kernel 2: out = h Wd, f32 out.  256m x 128n ----------------
// 512 thr / 8 waves (4m x 2n), wave 64x64. Grid 64e x 2mb x 8nb = 1024.
// LDS 96KB: A bf16 [256][128B] 2x32KB @0; Bd^T [128][128B] 2x16KB @65536.
__global__ __launch_bounds__(512, 2) void down_kernel_v3(
    const unsigned short* __restrict__ hin, const float* __restrict__ wd,
    float* __restrict__ out)
{
  __shared__ unsigned char smem[98304];
  const int t = threadIdx.x;
  int bid = blockIdx.x;
  bid = (bid & 7) * 128 + (bid >> 3);          // XCD-bijective (1024 = 8*128)
  const int e = bid >> 4, rr = bid & 15, mb = rr >> 3, nb = rr & 7;
  const int row0 = e * CAP + mb * 256;
  const int col0 = nb * 128;
  const unsigned short* Ag = hin + (size_t)row0 * DIM_F;
  const float* Bdg = wd + (size_t)e * (DIM_F * DIM_H) + col0;

  const int lane = t & 63, wid = t >> 6;
  const int wm = wid >> 1, wn = wid & 1;

  f32x4 acc[4][4];
  #pragma unroll
  for (int i = 0; i < 4; i++)
    #pragma unroll
    for (int j = 0; j < 4; j++) acc[i][j] = f32x4{0.f, 0.f, 0.f, 0.f};

  const int bn = t & 127, bkb = (t >> 7) * 16;
  float bs[16];

  auto loadB = [&](int k0) {
    #pragma unroll
    for (int i = 0; i < 16; i++)
      bs[i] = Bdg[(size_t)(k0 + bkb + i) * DIM_H + bn];
  };
  auto writeB = [&](int b) {
    const int Bb = 65536 + b * 16384;
    #pragma unroll
    for (int j = 0; j < 4; j++) {
      int off = Bb + bn * 128 + (((bkb + j * 4) * 2) ^ ((bn & 7) << 4));
      *reinterpret_cast<uint2*>(&smem[off]) =
          make_uint2(cvtpk(bs[j*4+0], bs[j*4+1]), cvtpk(bs[j*4+2], bs[j*4+3]));
    }
  };
  auto loadA = [&](int k0, int buf) {
    #pragma unroll
    for (int j = 0; j < 4; j++) {
      int lin = (j * 512 + t) * 16;
      int r = lin >> 7;
      int q = (lin >> 4) & 7;
      const void* src = (const unsigned char*)Ag + (size_t)r * 2048 + k0 * 2 + ((q ^ (r & 7)) * 16);
      gload_lds16(src, &smem[buf * 32768 + lin]);
    }
  };
  auto compute = [&](int kt) {
    const int Ab = (kt & 1) * 32768;
    const int Bb = 65536 + (kt & 1) * 16384;
    __builtin_amdgcn_s_setprio(1);
    #pragma unroll
    for (int kk = 0; kk < 2; kk++) {
      short8 a[4], b[4];
      #pragma unroll
      for (int mi = 0; mi < 4; mi++) {
        int r = wm * 64 + mi * 16 + (lane & 15);
        a[mi] = *reinterpret_cast<const short8*>(
            &smem[Ab + r * 128 + ((kk * 64 + (lane >> 4) * 16) ^ ((r & 7) << 4))]);
      }
      #pragma unroll
      for (int ni = 0; ni < 4; ni++) {
        int n = wn * 64 + ni * 16 + (lane & 15);
        b[ni] = *reinterpret_cast<const short8*>(
            &smem[Bb + n * 128 + ((kk * 64 + (lane >> 4) * 16) ^ ((n & 7) << 4))]);
      }
      #pragma unroll
      for (int mi = 0; mi < 4; mi++)
        #pragma unroll
        for (int ni = 0; ni < 4; ni++)
          acc[mi][ni] = __builtin_amdgcn_mfma_f32_16x16x32_bf16(a[mi], b[ni], acc[mi][ni], 0, 0, 0);
    }
    __builtin_amdgcn_s_setprio(0);
  };

  const int NT = DIM_F / 64;   // 16
  loadB(0);
  loadA(0, 0);
  VMCNT(4); SCHED0;            // 16 B scalars done; 4 A gloads in flight
  writeB(0);
  LGKMCNT0; VMCNT(0); SCHED0;
  SBAR;
  for (int kt = 0; kt < NT; kt++) {
    if (kt + 1 < NT) {
      loadB((kt + 1) * 64);
      loadA((kt + 1) * 64, (kt + 1) & 1);
      SCHED0;
    }
    compute(kt);
    if (kt + 1 < NT) {
      VMCNT(4); SCHED0;
      writeB((kt + 1) & 1);
      LGKMCNT0; VMCNT(0); SCHED0;
      SBAR;
    }
  }

  #pragma unroll
  for (int mi = 0; mi < 4; mi++)
    #pragma unroll
    for (int ni = 0; ni < 4; ni++) {
      int col = col0 + wn * 64 + ni * 16 + (lane & 15);
      int rbase = row0 + wm * 64 + mi * 16 + (lane >> 4) * 4;
      #pragma unroll
      for (int j = 0; j < 4; j++)
        out[(size_t)(rbase + j) * DIM_H + col] = acc[mi][ni][j];
    }
}

extern "C" void kernel_launch(void* const* d_in, const int* in_sizes, int n_in,
                              void* d_out, int out_size, void* d_ws, size_t ws_size,
                              hipStream_t stream) {
  (void)in_sizes; (void)n_in; (void)out_size; (void)ws_size;
  const float* x  = (const float*)d_in[0];
  // d_in[1] = tokens_per_expert: equal-count setup (C=512 each), static dispatch.
  const float* wg = (const float*)d_in[2];
  const float* wu = (const float*)d_in[3];
  const float* wd = (const float*)d_in[4];
  unsigned short* h   = (unsigned short*)d_ws;                        // 64 MiB
  unsigned short* xbf = (unsigned short*)((char*)d_ws + (size_t)NTOK * DIM_F * 2); // 64 MiB
  float* out = (float*)d_out;

  cvt_kernel<<<dim3((NTOK * DIM_H) / (256 * 8)), dim3(256), 0, stream>>>(x, xbf);
  gateup_kernel_v3<<<dim3(1024), dim3(512), 0, stream>>>(xbf, wg, wu, h);
  down_kernel_v3<<<dim3(1024), dim3(512), 0, stream>>>(h, wd, out);
}